// Round 1
// baseline (55.407 us; speedup 1.0000x reference)
//
#include <hip/hip_runtime.h>

// HalutMatmul forward on MI355X.
// Per row n: h[c][p] = sum_d I[n, c*9+d] * A[c][d][p]   (c=0..15, p=0..3)
//            code_c  = 4-level tree descent: bit_l = (h[c][l] > T[c*15 + node_l])
//            out[n][m] = sum_c L[m][c][code_c]
// S and B from the reference are structural (selection / path-sign matrices) and
// are baked into the control flow here.

#define NROWS (1024 * 128)

__global__ __launch_bounds__(256) void halut_fwd(
    const float* __restrict__ I,
    const float* __restrict__ A,
    const float* __restrict__ T,
    const float* __restrict__ L,
    float* __restrict__ out)
{
    // L in LDS, original [m][c*16+k] layout: gather for fixed (m,c) across 64
    // lanes hits <=16 distinct addresses on 16 distinct banks -> conflict-free.
    __shared__ float  sL[64 * 256];   // 64 KiB
    __shared__ double sA[576];        // A promoted to f64: [c][d][p]
    __shared__ double sT[240];        // thresholds promoted to f64

    const int tid = threadIdx.x;

    {   // stage L (16384 floats = 4096 float4)
        const float4* Lv  = (const float4*)L;
        float4*       sLv = (float4*)sL;
        #pragma unroll
        for (int i = 0; i < 16; ++i)
            sLv[i * 256 + tid] = Lv[i * 256 + tid];
    }
    for (int i = tid; i < 576; i += 256) sA[i] = (double)A[i];
    if (tid < 240) sT[tid] = (double)T[tid];
    __syncthreads();

    const int    row = blockIdx.x * 256 + tid;
    const float* rp  = I + (size_t)row * 144;

    float acc[64];
    #pragma unroll
    for (int m = 0; m < 64; ++m) acc[m] = 0.0f;

    #pragma unroll
    for (int g = 0; g < 4; ++g) {            // 4 codebooks per group, 36 floats
        float4 buf[9];
        const float4* rv = (const float4*)(rp + g * 36);  // 144B-aligned
        #pragma unroll
        for (int i = 0; i < 9; ++i) buf[i] = rv[i];
        const float* bf = (const float*)buf;

        #pragma unroll
        for (int cc = 0; cc < 4; ++cc) {
            const int c = g * 4 + cc;
            // per-codebook soft hash in f64 (decision boundary safety)
            double h0 = 0.0, h1 = 0.0, h2 = 0.0, h3 = 0.0;
            #pragma unroll
            for (int d = 0; d < 9; ++d) {
                const double  x  = (double)bf[cc * 9 + d];
                const double* ap = &sA[(c * 9 + d) * 4];
                h0 = fma(x, ap[0], h0);
                h1 = fma(x, ap[1], h1);
                h2 = fma(x, ap[2], h2);
                h3 = fma(x, ap[3], h3);
            }
            // tree descent; node_l = (2^l - 1) + prefix
            const double* tp = &sT[c * 15];
            int p;
            p =         (h0 > tp[0]);
            p = 2 * p + (h1 > tp[1 + p]);
            p = 2 * p + (h2 > tp[3 + p]);
            p = 2 * p + (h3 > tp[7 + p]);
            // gather-accumulate this codebook's LUT column
            const float* lp = &sL[c * 16 + p];
            #pragma unroll
            for (int m = 0; m < 64; ++m) acc[m] += lp[m * 256];
        }
    }

    float4* op = (float4*)(out + (size_t)row * 64);
    #pragma unroll
    for (int i = 0; i < 16; ++i)
        op[i] = make_float4(acc[4*i], acc[4*i+1], acc[4*i+2], acc[4*i+3]);
}

extern "C" void kernel_launch(void* const* d_in, const int* in_sizes, int n_in,
                              void* d_out, int out_size, void* d_ws, size_t ws_size,
                              hipStream_t stream) {
    const float* I = (const float*)d_in[0];
    const float* A = (const float*)d_in[1];
    const float* T = (const float*)d_in[2];
    const float* L = (const float*)d_in[3];
    float* outp = (float*)d_out;

    const int nblocks = NROWS / 256;   // 512 blocks of 256 threads, 1 row/thread
    halut_fwd<<<nblocks, 256, 0, stream>>>(I, A, T, L, outp);
}